// Round 7
// baseline (146.791 us; speedup 1.0000x reference)
//
#include <hip/hip_runtime.h>

#define N_NODES 40000
#define N_EDGES 640000
#define NFEAT   128
#define H1      128   // 2*NHID
#define H2      64    // NHID
#define NBLK    40    // ceil(40000/1024)

// ---- workspace layout (byte offsets, all 256-aligned) ----
#define OFF_SUP1   0UL          // 40000*128 bf16 = 10,240,000
#define OFF_H      10240000UL   // 40000*128 bf16 = 10,240,000
#define OFF_SUP2   20480000UL   // 40000*64  bf16 =  5,120,000
#define OFF_ROWPTR 25600000UL   // 40001 i32 -> 160,256 (padded)
#define OFF_RANK   25760256UL   // 640000 i32 -> 2,560,000
#define OFF_CNT    28320256UL   // 40000 i32 -> 160,000
#define OFF_BLKSUM 28480256UL   // 40 i32 -> 256
#define OFF_PREC   28480512UL   // 640000 u32 packed (src<<16 | bf16 w) -> 2,560,000
#define OFF_W1T    31040512UL   // 128*128 bf16 -> 32,768
#define OFF_W2T    31073280UL   // 64*128 bf16 -> 16,384
// total 31,089,664 bytes

typedef unsigned int uint;
typedef unsigned short ushort;
typedef __attribute__((ext_vector_type(8))) short bf16x8;
typedef __attribute__((ext_vector_type(4))) float f32x4;
typedef __attribute__((ext_vector_type(2))) float f32x2;

// bf16 helpers (bit-level, round-to-nearest-even on pack)
__device__ __forceinline__ float bl(uint u) { union { uint i; float f; } c; c.i = u << 16; return c.f; }
__device__ __forceinline__ float bh(uint u) { union { uint i; float f; } c; c.i = u & 0xFFFF0000u; return c.f; }
__device__ __forceinline__ ushort f2b(float f) {
    union { float f; uint i; } c; c.f = f;
    uint u = c.i + 0x7FFFu + ((c.i >> 16) & 1u);
    return (ushort)(u >> 16);
}

// zero cnt + W1 [128][128] f32 -> W1T [n][k] bf16 ; W2 [128][64] f32 -> W2T [n][k] bf16
__global__ void init_k(int* __restrict__ cnt,
                       const float* __restrict__ W1, const float* __restrict__ W2,
                       ushort* __restrict__ W1T, ushort* __restrict__ W2T) {
    const int i = blockIdx.x * 256 + threadIdx.x;
    if (i < N_NODES) cnt[i] = 0;
    if (i < 128 * 128) {
        const int c = i >> 7, k = i & 127;
        W1T[i] = f2b(W1[k * 128 + c]);
    }
    if (i < 64 * 128) {
        const int c = i >> 7, k = i & 127;
        W2T[i] = f2b(W2[k * 64 + c]);
    }
}

// histogram + per-edge rank within its dst (coalesced rank write)
__global__ void hist_k(const int* __restrict__ edst, int* __restrict__ cnt,
                       int* __restrict__ rank) {
    int i = blockIdx.x * blockDim.x + threadIdx.x;
    if (i < N_EDGES) rank[i] = atomicAdd(&cnt[edst[i]], 1);
}

// per-1024-block sums
__global__ __launch_bounds__(1024) void reduce_k(const int* __restrict__ cnt,
                                                 int* __restrict__ blksum) {
    __shared__ int ws[16];
    const int t = threadIdx.x;
    const int idx = blockIdx.x * 1024 + t;
    int v = (idx < N_NODES) ? cnt[idx] : 0;
#pragma unroll
    for (int d = 1; d < 64; d <<= 1) v += __shfl_xor(v, d);
    if ((t & 63) == 0) ws[t >> 6] = v;
    __syncthreads();
    if (t < 16) {
        int s = ws[t];
#pragma unroll
        for (int d = 1; d < 16; d <<= 1) s += __shfl_xor(s, d);
        if (t == 0) blksum[blockIdx.x] = s;
    }
}

// full scan: each block inline-scans the 40 block sums (wave 0) + local scan
__global__ __launch_bounds__(1024) void scan3_k(const int* __restrict__ cnt,
                                                const int* __restrict__ blksum,
                                                int* __restrict__ row_ptr) {
    __shared__ int wsum[16];
    __shared__ int bpref;
    const int t = threadIdx.x, lane = t & 63, wv = t >> 6;
    const int idx = blockIdx.x * 1024 + t;
    const int v = (idx < N_NODES) ? cnt[idx] : 0;
    int incl = v;
#pragma unroll
    for (int d = 1; d < 64; d <<= 1) {
        int o = __shfl_up(incl, d);
        if (lane >= d) incl += o;
    }
    if (lane == 63) wsum[wv] = incl;
    if (t < 64) {  // wave 0: inclusive scan of the 40 block sums
        int s = (t < NBLK) ? blksum[t] : 0;
#pragma unroll
        for (int d = 1; d < 64; d <<= 1) {
            int o = __shfl_up(s, d);
            if (t >= d) s += o;
        }
        if (blockIdx.x == 0) { if (t == 0) bpref = 0; }
        else if (t == blockIdx.x - 1) bpref = s;
    }
    __syncthreads();
    if (t < 16) {
        int s = wsum[t];
#pragma unroll
        for (int d = 1; d < 16; d <<= 1) {
            int o = __shfl_up(s, d);
            if (t >= d) s += o;
        }
        wsum[t] = s;
    }
    __syncthreads();
    const int base = bpref + (wv ? wsum[wv - 1] : 0);
    if (idx < N_NODES) row_ptr[idx + 1] = base + incl;
    if (idx == 0) row_ptr[0] = 0;
}

// fused: blocks with bid%8==0 (one XCD under round-robin mapping) grid-stride the
// scatter with REGULAR stores (prec 2.56MB merges in that XCD's 4MB L2); the rest
// run gemm1 MFMA tiles. Correctness independent of the XCD mapping.
__global__ __launch_bounds__(256) void scatgemm1_k(const int* __restrict__ esrc,
                                                   const int* __restrict__ edst,
                                                   const float* __restrict__ ew,
                                                   const int* __restrict__ rp,
                                                   const int* __restrict__ rank,
                                                   uint* __restrict__ prec,
                                                   const float* __restrict__ x,
                                                   const ushort* __restrict__ WT,
                                                   ushort* __restrict__ outS) {
    const int bid = blockIdx.x;
    if ((bid & 7) == 0) {
        // scatter role: 391 blocks (bid = 0,8,...,3120), grid-stride
        for (int i = (bid >> 3) * 256 + (int)threadIdx.x; i < N_EDGES; i += 391 * 256) {
            const int pos = rp[edst[i]] + rank[i];
            const uint rec = ((uint)esrc[i] << 16) | (uint)f2b(ew[i]);
            prec[pos] = rec;
        }
        return;
    }
    // gemm1 role: gid = #non-scatter blocks before bid
    const int gid = bid - (bid >> 3) - 1;
    if (gid >= 625) return;
    const int lane = threadIdx.x & 63;
    const int m0 = gid * 64 + (threadIdx.x >> 6) * 16;
    const int r = lane & 15, kg = lane >> 4;

    bf16x8 a[4];
    const float* xp = x + (size_t)(m0 + r) * 128 + kg * 8;
#pragma unroll
    for (int kt = 0; kt < 4; ++kt) {
        float xf[8];
        *(float4*)(xf)     = *(const float4*)(xp + kt * 32);
        *(float4*)(xf + 4) = *(const float4*)(xp + kt * 32 + 4);
        bf16x8 v;
#pragma unroll
        for (int i = 0; i < 8; ++i) v[i] = (short)f2b(xf[i]);
        a[kt] = v;
    }

#pragma unroll
    for (int nt = 0; nt < 8; ++nt) {
        const ushort* wp = WT + (size_t)(nt * 16 + r) * 128 + kg * 8;
        f32x4 acc = {0.f, 0.f, 0.f, 0.f};
#pragma unroll
        for (int kt = 0; kt < 4; ++kt) {
            const bf16x8 bfr = *(const bf16x8*)(wp + kt * 32);
            acc = __builtin_amdgcn_mfma_f32_16x16x32_bf16(a[kt], bfr, acc, 0, 0, 0);
        }
#pragma unroll
        for (int q = 0; q < 4; ++q)
            outS[(size_t)(m0 + kg * 4 + q) * 128 + nt * 16 + r] = f2b(acc[q]);
    }
}

// sup2 = h @ W2  (M=40000, K=128, N=64) — MFMA bf16, bf16 in.
__global__ __launch_bounds__(256) void gemm2_k(const ushort* __restrict__ h,
                                               const ushort* __restrict__ WT,
                                               ushort* __restrict__ out) {
    const int lane = threadIdx.x & 63;
    const int m0 = blockIdx.x * 64 + (threadIdx.x >> 6) * 16;
    const int r = lane & 15, kg = lane >> 4;

    bf16x8 a[4];
    const ushort* hp = h + (size_t)(m0 + r) * 128 + kg * 8;
#pragma unroll
    for (int kt = 0; kt < 4; ++kt) a[kt] = *(const bf16x8*)(hp + kt * 32);

#pragma unroll
    for (int nt = 0; nt < 4; ++nt) {
        const ushort* wp = WT + (size_t)(nt * 16 + r) * 128 + kg * 8;
        f32x4 acc = {0.f, 0.f, 0.f, 0.f};
#pragma unroll
        for (int kt = 0; kt < 4; ++kt) {
            const bf16x8 bfr = *(const bf16x8*)(wp + kt * 32);
            acc = __builtin_amdgcn_mfma_f32_16x16x32_bf16(a[kt], bfr, acc, 0, 0, 0);
        }
#pragma unroll
        for (int q = 0; q < 4; ++q)
            out[(size_t)(m0 + kg * 4 + q) * 64 + nt * 16 + r] = f2b(acc[q]);
    }
}

// h = relu( spmm(adj, sup1) + b1 ).  Wave per node; lanes 0-31 take even edges,
// lanes 32-63 odd edges; each lane gathers 8B (feats 4*l32..+3). 4 gathers in flight.
__global__ __launch_bounds__(256) void spmm1_k(const ushort* __restrict__ sup,
                                               const int* __restrict__ rp,
                                               const uint* __restrict__ prec,
                                               const float* __restrict__ b,
                                               ushort* __restrict__ h) {
    const int wid = blockIdx.x * 4 + (threadIdx.x >> 6);
    const int lane = threadIdx.x & 63;
    const int half = lane >> 5, l32 = lane & 31;
    const int e0 = rp[wid], e1 = rp[wid + 1];
    const uint2* sup64 = (const uint2*)sup;
    float c0 = 0.f, c1 = 0.f, c2 = 0.f, c3 = 0.f, c4 = 0.f, c5 = 0.f, c6 = 0.f, c7 = 0.f;
    int e = e0;
    for (; e + 8 <= e1; e += 8) {
        const uint r0 = prec[e + half],     r1 = prec[e + 2 + half];
        const uint r2 = prec[e + 4 + half], r3 = prec[e + 6 + half];
        const uint2 v0 = sup64[((size_t)(r0 >> 16) << 5) + l32];
        const uint2 v1 = sup64[((size_t)(r1 >> 16) << 5) + l32];
        const uint2 v2 = sup64[((size_t)(r2 >> 16) << 5) + l32];
        const uint2 v3 = sup64[((size_t)(r3 >> 16) << 5) + l32];
        const float w0 = bl(r0), w1 = bl(r1), w2 = bl(r2), w3 = bl(r3);
        c0 = fmaf(w0, bl(v0.x), c0); c1 = fmaf(w0, bh(v0.x), c1);
        c2 = fmaf(w0, bl(v0.y), c2); c3 = fmaf(w0, bh(v0.y), c3);
        c4 = fmaf(w1, bl(v1.x), c4); c5 = fmaf(w1, bh(v1.x), c5);
        c6 = fmaf(w1, bl(v1.y), c6); c7 = fmaf(w1, bh(v1.y), c7);
        c0 = fmaf(w2, bl(v2.x), c0); c1 = fmaf(w2, bh(v2.x), c1);
        c2 = fmaf(w2, bl(v2.y), c2); c3 = fmaf(w2, bh(v2.y), c3);
        c4 = fmaf(w3, bl(v3.x), c4); c5 = fmaf(w3, bh(v3.x), c5);
        c6 = fmaf(w3, bl(v3.y), c6); c7 = fmaf(w3, bh(v3.y), c7);
    }
    for (; e + 2 <= e1; e += 2) {
        const uint r0 = prec[e + half];
        const uint2 v0 = sup64[((size_t)(r0 >> 16) << 5) + l32];
        const float w0 = bl(r0);
        c0 = fmaf(w0, bl(v0.x), c0); c1 = fmaf(w0, bh(v0.x), c1);
        c2 = fmaf(w0, bl(v0.y), c2); c3 = fmaf(w0, bh(v0.y), c3);
    }
    if (e < e1 && half == 0) {
        const uint r0 = prec[e];
        const uint2 v0 = sup64[((size_t)(r0 >> 16) << 5) + l32];
        const float w0 = bl(r0);
        c0 = fmaf(w0, bl(v0.x), c0); c1 = fmaf(w0, bh(v0.x), c1);
        c2 = fmaf(w0, bl(v0.y), c2); c3 = fmaf(w0, bh(v0.y), c3);
    }
    float f0 = c0 + c4, f1 = c1 + c5, f2 = c2 + c6, f3 = c3 + c7;
    f0 += __shfl_xor(f0, 32); f1 += __shfl_xor(f1, 32);
    f2 += __shfl_xor(f2, 32); f3 += __shfl_xor(f3, 32);
    if (half == 0) {
        const float4 bb = ((const float4*)b)[l32];
        f0 = fmaxf(f0 + bb.x, 0.f);
        f1 = fmaxf(f1 + bb.y, 0.f);
        f2 = fmaxf(f2 + bb.z, 0.f);
        f3 = fmaxf(f3 + bb.w, 0.f);
        uint2 pk;
        pk.x = (uint)f2b(f0) | ((uint)f2b(f1) << 16);
        pk.y = (uint)f2b(f2) | ((uint)f2b(f3) << 16);
        ((uint2*)h)[(size_t)wid * 32 + l32] = pk;
    }
}

// out = spmm(adj, sup2) + b2.  Wave per node; half-wave per edge, 4B/lane gathers.
__global__ __launch_bounds__(256) void spmm2_k(const ushort* __restrict__ sup,
                                               const int* __restrict__ rp,
                                               const uint* __restrict__ prec,
                                               const float* __restrict__ b,
                                               float* __restrict__ out) {
    const int wid = blockIdx.x * 4 + (threadIdx.x >> 6);
    const int lane = threadIdx.x & 63;
    const int half = lane >> 5, l32 = lane & 31;
    const int e0 = rp[wid], e1 = rp[wid + 1];
    const uint* sup32 = (const uint*)sup;
    float d0 = 0.f, d1 = 0.f, d2 = 0.f, d3 = 0.f;
    int e = e0;
    for (; e + 8 <= e1; e += 8) {
        const uint r0 = prec[e + half],     r1 = prec[e + 2 + half];
        const uint r2 = prec[e + 4 + half], r3 = prec[e + 6 + half];
        const uint v0 = sup32[((size_t)(r0 >> 16) << 5) + l32];
        const uint v1 = sup32[((size_t)(r1 >> 16) << 5) + l32];
        const uint v2 = sup32[((size_t)(r2 >> 16) << 5) + l32];
        const uint v3 = sup32[((size_t)(r3 >> 16) << 5) + l32];
        d0 = fmaf(bl(r0), bl(v0), d0); d1 = fmaf(bl(r0), bh(v0), d1);
        d2 = fmaf(bl(r1), bl(v1), d2); d3 = fmaf(bl(r1), bh(v1), d3);
        d0 = fmaf(bl(r2), bl(v2), d0); d1 = fmaf(bl(r2), bh(v2), d1);
        d2 = fmaf(bl(r3), bl(v3), d2); d3 = fmaf(bl(r3), bh(v3), d3);
    }
    for (; e + 2 <= e1; e += 2) {
        const uint r0 = prec[e + half];
        const uint v0 = sup32[((size_t)(r0 >> 16) << 5) + l32];
        d0 = fmaf(bl(r0), bl(v0), d0); d1 = fmaf(bl(r0), bh(v0), d1);
    }
    if (e < e1 && half == 0) {
        const uint r0 = prec[e];
        const uint v0 = sup32[((size_t)(r0 >> 16) << 5) + l32];
        d0 = fmaf(bl(r0), bl(v0), d0); d1 = fmaf(bl(r0), bh(v0), d1);
    }
    float g0 = d0 + d2, g1 = d1 + d3;
    g0 += __shfl_xor(g0, 32); g1 += __shfl_xor(g1, 32);
    if (half == 0) {
        const float2 bb = ((const float2*)b)[l32];
        f32x2 res = {g0 + bb.x, g1 + bb.y};
        __builtin_nontemporal_store(res, (f32x2*)out + (size_t)wid * 32 + l32);
    }
}

extern "C" void kernel_launch(void* const* d_in, const int* in_sizes, int n_in,
                              void* d_out, int out_size, void* d_ws, size_t ws_size,
                              hipStream_t stream) {
    const float* x    = (const float*)d_in[0];
    const int*   esrc = (const int*)d_in[1];
    const int*   edst = (const int*)d_in[2];
    const float* ew   = (const float*)d_in[3];
    const float* W1   = (const float*)d_in[4];
    const float* b1   = (const float*)d_in[5];
    const float* W2   = (const float*)d_in[6];
    const float* b2   = (const float*)d_in[7];
    float* out = (float*)d_out;

    char* ws = (char*)d_ws;
    ushort* sup1   = (ushort*)(ws + OFF_SUP1);
    ushort* h      = (ushort*)(ws + OFF_H);
    ushort* sup2   = (ushort*)(ws + OFF_SUP2);
    int*   row_ptr = (int*)(ws + OFF_ROWPTR);
    int*   rank    = (int*)(ws + OFF_RANK);
    int*   cnt     = (int*)(ws + OFF_CNT);
    int*   blksum  = (int*)(ws + OFF_BLKSUM);
    uint*  prec    = (uint*)(ws + OFF_PREC);
    ushort* W1T    = (ushort*)(ws + OFF_W1T);
    ushort* W2T    = (ushort*)(ws + OFF_W2T);

    // CSR build + weight prep
    init_k<<<157, 256, 0, stream>>>(cnt, W1, W2, W1T, W2T);
    hist_k<<<2500, 256, 0, stream>>>(edst, cnt, rank);
    reduce_k<<<NBLK, 1024, 0, stream>>>(cnt, blksum);
    scan3_k<<<NBLK, 1024, 0, stream>>>(cnt, blksum, row_ptr);
    scatgemm1_k<<<3125, 256, 0, stream>>>(esrc, edst, ew, row_ptr, rank, prec, x, W1T, sup1);

    // layer 1 aggregate
    spmm1_k<<<10000, 256, 0, stream>>>(sup1, row_ptr, prec, b1, h);

    // layer 2
    gemm2_k<<<625, 256, 0, stream>>>(h, W2T, sup2);
    spmm2_k<<<10000, 256, 0, stream>>>(sup2, row_ptr, prec, b2, out);
}